// Round 9
// baseline (121.212 us; speedup 1.0000x reference)
//
#include <hip/hip_runtime.h>
#include <hip/hip_bf16.h>

// Problem: B=4, S=2048, D=512, H=8, KD=VD=64.
// out[b,s,:] = concat_h( softmax(qk^T*scale_h) @ (v*mask_j) * mask_i ) @ Wo
// Softmax denominator is UNMASKED (mask applied post-softmax, per reference).
// v5: fp16 pipeline; attention split-K x4 (2048 blocks, 6 blocks/CU) with
// normalized fp16 partials + logsumexp combine; VALU trims (tree max, fdot2).

typedef _Float16 f16x8 __attribute__((ext_vector_type(8)));
typedef float    f32x4  __attribute__((ext_vector_type(4)));
typedef float    f32x16 __attribute__((ext_vector_type(16)));
typedef __fp16   hf2 __attribute__((ext_vector_type(2)));

#define BB 4
#define SS 2048
#define DD 512
#define HH 8
#define KDIM 64
#define NSPLIT 4
#define TPS 8   // K-tiles per split (32/NSPLIT)

#define EXP2F(x) __builtin_amdgcn_exp2f(x)

#define GLOAD_LDS16(gp, lp)                                                   \
  __builtin_amdgcn_global_load_lds(                                          \
      (const __attribute__((address_space(1))) void*)(gp),                    \
      (__attribute__((address_space(3))) void*)(lp), 16, 0, 0)

// swizzled byte offset within a [rows][64] fp16 tile (128B rows)
#define SWZ(row, bc) ((row) * 128 + ((bc) ^ (((row) & 7) << 4)))

static __device__ __forceinline__ unsigned pk2(float a, float b) {
  auto h = __builtin_amdgcn_cvt_pkrtz(a, b);  // __fp16 ext_vector(2)
  return __builtin_bit_cast(unsigned, h);
}

union PU { unsigned u[4]; f16x8 v; };

// ---------------- convert_x: x fp32 -> xf fp16 [8192,512] --------------------
__global__ __launch_bounds__(256) void convert_x(
    const float* __restrict__ x, _Float16* __restrict__ xf) {
  size_t i = ((size_t)blockIdx.x * 256 + threadIdx.x) * 8;
  float4 a = *(const float4*)&x[i];
  float4 b = *(const float4*)&x[i + 4];
  float vv[8] = {a.x, a.y, a.z, a.w, b.x, b.y, b.z, b.w};
  _Float16 hb[8];
#pragma unroll
  for (int u = 0; u < 8; ++u) hb[u] = (_Float16)vv[u];
  *(uint4*)&xf[i] = *(uint4*)hb;
}

// ---------------- convert_w: Wq/Wk/Wv [8,512,64] -> wtf fp16 [1536][512] -----
__global__ __launch_bounds__(256) void convert_w(
    const float* __restrict__ Wq, const float* __restrict__ Wk,
    const float* __restrict__ Wv, _Float16* __restrict__ wtf) {
  __shared__ float s_tile[64][65];
  const int t = threadIdx.x;
  const int kb = blockIdx.x;          // 0..7
  const int hw = blockIdx.y;          // 0..23
  const int which = hw >> 3, h = hw & 7;
  const float* W = (which == 0) ? Wq : (which == 1) ? Wk : Wv;
  const float* src = W + (size_t)h * DD * KDIM + (size_t)kb * 64 * KDIM;

  {
    int kk = t >> 2, c0 = (t & 3) * 16;
#pragma unroll
    for (int u = 0; u < 4; ++u)
      *(float4*)&s_tile[kk][c0 + u * 4] = *(const float4*)&src[kk * KDIM + c0 + u * 4];
  }
  __syncthreads();

  int kd = t >> 2, kk0 = (t & 3) * 16;
  int n = which * 512 + h * 64 + kd;
  _Float16 hb[16];
#pragma unroll
  for (int u = 0; u < 16; ++u) hb[u] = (_Float16)s_tile[kk0 + u][kd];
  size_t off = (size_t)n * DD + kb * 64 + kk0;
  *(uint4*)&wtf[off] = *(uint4*)&hb[0];
  *(uint4*)&wtf[off + 8] = *(uint4*)&hb[8];
}

// ---------------- convert_wo: Wo [512,64] -> WoT fp16 [64][512] --------------
__global__ __launch_bounds__(256) void convert_wo(
    const float* __restrict__ Wo, _Float16* __restrict__ woT) {
  __shared__ float s_tile[64][65];
  const int t = threadIdx.x;
  const int kb = blockIdx.x;          // 0..7 over K rows
  const float* src = Wo + (size_t)kb * 64 * 64;
  {
    int kk = t >> 2, c0 = (t & 3) * 16;
#pragma unroll
    for (int u = 0; u < 4; ++u)
      *(float4*)&s_tile[kk][c0 + u * 4] = *(const float4*)&src[kk * 64 + c0 + u * 4];
  }
  __syncthreads();
  int col = t >> 2, kk0 = (t & 3) * 16;
  _Float16 hb[16];
#pragma unroll
  for (int u = 0; u < 16; ++u) hb[u] = (_Float16)s_tile[kk0 + u][col];
  size_t off = (size_t)col * DD + kb * 64 + kk0;
  *(uint4*)&woT[off] = *(uint4*)&hb[0];
  *(uint4*)&woT[off + 8] = *(uint4*)&hb[8];
}

// ---------------- qkv_gemm: [8192,512] @ [512,1536] fp16 MFMA ----------------
__global__ __launch_bounds__(256) void qkv_gemm(
    const _Float16* __restrict__ xf, const _Float16* __restrict__ wtf,
    const float* __restrict__ mask, const float* __restrict__ scales,
    _Float16* __restrict__ qf, _Float16* __restrict__ kf,
    _Float16* __restrict__ vT) {
  __shared__ _Float16 Af[128 * 32], Bf[128 * 32];
  const int t = threadIdx.x, l = t & 63, w = t >> 6;
  const int wr = w >> 1, wc = w & 1;
  const int m0 = blockIdx.y * 128, n0 = blockIdx.x * 128;

  f32x4 acc[4][4];
#pragma unroll
  for (int m = 0; m < 4; ++m)
#pragma unroll
    for (int n = 0; n < 4; ++n) acc[m][n] = f32x4{0.f, 0.f, 0.f, 0.f};

  const int rl = l >> 2, ce = (l & 3) * 8;

  for (int kt = 0; kt < 16; ++kt) {
    const int k0 = kt * 32;
    __syncthreads();
#pragma unroll
    for (int i = 0; i < 2; ++i) {
      const int row = w * 32 + i * 16;
      const size_t aoff = (size_t)(m0 + row + rl) * DD + k0 + ce;
      const size_t boff = (size_t)(n0 + row + rl) * DD + k0 + ce;
      GLOAD_LDS16(xf + aoff, &Af[row * 32]);
      GLOAD_LDS16(wtf + boff, &Bf[row * 32]);
    }
    __syncthreads();

    f16x8 ah[4], bh[4];
#pragma unroll
    for (int m = 0; m < 4; ++m) {
      int r = wr * 64 + m * 16 + (l & 15);
      ah[m] = *(const f16x8*)&Af[r * 32 + (l >> 4) * 8];
    }
#pragma unroll
    for (int n = 0; n < 4; ++n) {
      int r = wc * 64 + n * 16 + (l & 15);
      bh[n] = *(const f16x8*)&Bf[r * 32 + (l >> 4) * 8];
    }
#pragma unroll
    for (int m = 0; m < 4; ++m)
#pragma unroll
      for (int n = 0; n < 4; ++n)
        acc[m][n] = __builtin_amdgcn_mfma_f32_16x16x32_f16(ah[m], bh[n], acc[m][n], 0, 0, 0);
  }

#pragma unroll
  for (int n = 0; n < 4; ++n) {
    int colg = n0 + wc * 64 + n * 16 + (l & 15);
    int which = colg >> 9, rem = colg & 511;
    int h = rem >> 6, kd = rem & 63;
    float qsc = (which == 0) ? scales[h] * 1.44269504f : 1.f;
#pragma unroll
    for (int m = 0; m < 4; ++m) {
      int row0 = m0 + wr * 64 + m * 16 + (l >> 4) * 4;  // 4 consecutive rows
      if (which == 2) {
        int b = row0 >> 11, s0 = row0 & 2047;
        _Float16 tmp[4] __attribute__((aligned(8)));
#pragma unroll
        for (int j = 0; j < 4; ++j)
          tmp[j] = (_Float16)(acc[m][n][j] * mask[row0 + j]);
        *(uint2*)&vT[((size_t)(b * HH + h) * KDIM + kd) * SS + s0] = *(uint2*)tmp;
      } else {
        _Float16* dst = (which == 0) ? qf : kf;
#pragma unroll
        for (int j = 0; j < 4; ++j) {
          int row = row0 + j;
          int b = row >> 11, s = row & 2047;
          dst[(((size_t)b * HH + h) * SS + s) * KDIM + kd] =
              (_Float16)(acc[m][n][j] * qsc);
        }
      }
    }
  }
}

// ---------------- Kernel B: flash attention v5 (split-K x4) ------------------
// grid (S/128, B*H, NSPLIT) x 256 thr (4 waves). Wave w owns q rows w*32..+32.
// Lane owns q-row (l&31). QK^T: St = mfma(K, Q); PV: O^T = mfma(V, P).
// Partials: po = O/lsum (fp16), pli = m + log2(lsum) (fp32).
__global__ __launch_bounds__(256) void attn_kernel(
    const _Float16* __restrict__ qg, const _Float16* __restrict__ kg,
    const _Float16* __restrict__ vTg,
    _Float16* __restrict__ po, float* __restrict__ pli) {
  const int t = threadIdx.x;
  const int l = t & 63, w = t >> 6;
  const int lr = l & 31, hi = l >> 5;
  const int bh = blockIdx.y;
  const int q0 = blockIdx.x * 128;
  const int split = blockIdx.z;

  __shared__ _Float16 ksf[64 * 64];   // K tile, swizzled (8KB)
  __shared__ _Float16 vts[64 * 64];   // V^T tile, swizzled (8KB)

  const size_t base = (size_t)bh * SS * KDIM;
  const size_t vbase = (size_t)bh * KDIM * SS;

  // Q fragments from global (B-operand: col=q-row=lr, k = hi*8+j)
  f16x8 qfr[4];
  const int s_q = q0 + w * 32 + lr;
#pragma unroll
  for (int kb = 0; kb < 4; ++kb)
    qfr[kb] = *(const f16x8*)&qg[base + (size_t)s_q * KDIM + kb * 16 + hi * 8];

  float m_s = -1e30f, lsum = 0.f;
  f32x16 oacc[2] = {};

  const int kt0 = split * TPS;
  for (int kt = kt0; kt < kt0 + TPS; ++kt) {
    __syncthreads();
    // stage K + V^T, 8 rows per gload, pre-swizzled global source
#pragma unroll
    for (int c = 0; c < 2; ++c) {
      const int r = w * 16 + c * 8 + (l >> 3);
      const int ecol = ((l & 7) * 8) ^ (((l >> 3) & 7) * 8);
      size_t koff = base + (size_t)(kt * 64 + r) * KDIM + ecol;
      size_t voff = vbase + (size_t)r * SS + kt * 64 + ecol;
      GLOAD_LDS16(kg + koff, ksf + (w * 16 + c * 8) * 64);
      GLOAD_LDS16(vTg + voff, vts + (w * 16 + c * 8) * 64);
    }
    __syncthreads();

    // QK^T: St[key][qrow], A = K rows (jb*32+lr), B = Q
    f32x16 st2[2];
#pragma unroll
    for (int jb = 0; jb < 2; ++jb) {
      f32x16 acc = {};
      const int krow = jb * 32 + lr;
#pragma unroll
      for (int kb = 0; kb < 4; ++kb) {
        f16x8 kfr = *(const f16x8*)((const char*)ksf + SWZ(krow, kb * 32 + hi * 16));
        acc = __builtin_amdgcn_mfma_f32_32x32x16_f16(kfr, qfr[kb], acc, 0, 0, 0);
      }
      st2[jb] = acc;
    }

    // tile max: parallel tree (scores in exp2 domain via Q pre-scale)
    float m8[8];
#pragma unroll
    for (int i = 0; i < 8; ++i)
      m8[i] = fmaxf(fmaxf(st2[0][i], st2[0][i + 8]),
                    fmaxf(st2[1][i], st2[1][i + 8]));
    float m4a = fmaxf(m8[0], m8[1]), m4b = fmaxf(m8[2], m8[3]);
    float m4c = fmaxf(m8[4], m8[5]), m4d = fmaxf(m8[6], m8[7]);
    float mt = fmaxf(fmaxf(m4a, m4b), fmaxf(m4c, m4d));
    mt = fmaxf(mt, __shfl_xor(mt, 32, 64));

    // defer-max: rescale only if some lane grew past threshold
    if (!__all(mt <= m_s + 11.5f)) {
      float mn = fmaxf(m_s, mt);
      float rs = EXP2F(m_s - mn);
      m_s = mn;
      lsum *= rs;
#pragma unroll
      for (int nb = 0; nb < 2; ++nb)
#pragma unroll
        for (int rr = 0; rr < 16; ++rr) oacc[nb][rr] *= rs;
    }

    // P = exp2(St - m) packed to fp16 pairs in registers.
    // wds[jb][g] packs keys {jb*32 + g*8 + 4*hi + 0..3}.
    float ps0 = 0.f, ps1 = 0.f;
    unsigned wds[2][4][2];
#pragma unroll
    for (int jb = 0; jb < 2; ++jb)
#pragma unroll
      for (int g = 0; g < 4; ++g) {
        float p0 = EXP2F(st2[jb][g * 4 + 0] - m_s);
        float p1 = EXP2F(st2[jb][g * 4 + 1] - m_s);
        float p2 = EXP2F(st2[jb][g * 4 + 2] - m_s);
        float p3 = EXP2F(st2[jb][g * 4 + 3] - m_s);
        unsigned pa = pk2(p0, p1), pb = pk2(p2, p3);
        wds[jb][g][0] = pa;
        wds[jb][g][1] = pb;
#if __has_builtin(__builtin_amdgcn_fdot2)
        hf2 one2 = {(__fp16)1.f, (__fp16)1.f};
        ps0 = __builtin_amdgcn_fdot2(__builtin_bit_cast(hf2, pa), one2, ps0, false);
        ps1 = __builtin_amdgcn_fdot2(__builtin_bit_cast(hf2, pb), one2, ps1, false);
#else
        ps0 += p0 + p1;
        ps1 += p2 + p3;
#endif
      }
    float psum = ps0 + ps1;
    psum += __shfl_xor(psum, 32, 64);
    lsum += psum;

    // O^T += V P: B-frag for MFMA kb needs keys kb*16 + hi*8 + 0..7.
#pragma unroll
    for (int kb = 0; kb < 4; ++kb) {
      const int jb = kb >> 1, gb = (kb & 1) * 2;
      // send what the partner half needs: wds[jb][gb + 1 - hi]
      unsigned s0 = hi ? wds[jb][gb][0] : wds[jb][gb + 1][0];
      unsigned s1 = hi ? wds[jb][gb][1] : wds[jb][gb + 1][1];
      unsigned r0 = (unsigned)__shfl_xor((int)s0, 32, 64);
      unsigned r1 = (unsigned)__shfl_xor((int)s1, 32, 64);
      PU pu;
      pu.u[0] = hi ? r0 : wds[jb][gb][0];
      pu.u[1] = hi ? r1 : wds[jb][gb][1];
      pu.u[2] = hi ? wds[jb][gb + 1][0] : r0;
      pu.u[3] = hi ? wds[jb][gb + 1][1] : r1;
#pragma unroll
      for (int nb = 0; nb < 2; ++nb) {
        f16x8 vf = *(const f16x8*)((const char*)vts + SWZ(nb * 32 + lr, kb * 32 + hi * 16));
        oacc[nb] = __builtin_amdgcn_mfma_f32_32x32x16_f16(vf, pu.v, oacc[nb], 0, 0, 0);
      }
    }
  }

  // epilogue: normalized partial O (fp16) + logsumexp li (fp32)
  const float inv = 1.0f / lsum;
  const float li = m_s + __log2f(lsum);
  _Float16* prow = po + (((size_t)split * (BB * HH) + bh) * SS + s_q) * KDIM;
#pragma unroll
  for (int nb = 0; nb < 2; ++nb)
#pragma unroll
    for (int g = 0; g < 4; ++g) {
      uint2 o;
      o.x = pk2(oacc[nb][g * 4 + 0] * inv, oacc[nb][g * 4 + 1] * inv);
      o.y = pk2(oacc[nb][g * 4 + 2] * inv, oacc[nb][g * 4 + 3] * inv);
      *(uint2*)&prow[nb * 32 + g * 8 + hi * 4] = o;
    }
  if (hi == 0)
    pli[((size_t)split * (BB * HH) + bh) * SS + s_q] = li;
}

// ---------------- attn_combine: merge NSPLIT partials, apply mask_i ----------
// grid 2048 x 256. Thread: row = blk*32 + t>>3 (bh*2048+qrow), c = t&7 (vd8).
__global__ __launch_bounds__(256) void attn_combine(
    const _Float16* __restrict__ po, const float* __restrict__ pli,
    const float* __restrict__ mask, _Float16* __restrict__ ctxf) {
  const int t = threadIdx.x;
  const int row = blockIdx.x * 32 + (t >> 3);
  const int c = t & 7;
  const int bh = row >> 11, qrow = row & 2047;
  const int b = bh >> 3, h = bh & 7;
  const int NR = BB * HH * SS;  // rows per split

  float li[NSPLIT];
#pragma unroll
  for (int s = 0; s < NSPLIT; ++s) li[s] = pli[(size_t)s * NR + row];
  float L = fmaxf(fmaxf(li[0], li[1]), fmaxf(li[2], li[3]));
  float wgt[NSPLIT], wsum = 0.f;
#pragma unroll
  for (int s = 0; s < NSPLIT; ++s) { wgt[s] = EXP2F(li[s] - L); wsum += wgt[s]; }

  float acc[8] = {};
#pragma unroll
  for (int s = 0; s < NSPLIT; ++s) {
    uint4 u = *(const uint4*)&po[((size_t)s * NR + row) * KDIM + c * 8];
    const _Float16* hp = (const _Float16*)&u;
#pragma unroll
    for (int j = 0; j < 8; ++j) acc[j] += wgt[s] * (float)hp[j];
  }
  const float sc = mask[b * SS + qrow] / wsum;
  _Float16 ob[8] __attribute__((aligned(16)));
#pragma unroll
  for (int j = 0; j < 8; ++j) ob[j] = (_Float16)(acc[j] * sc);
  *(uint4*)&ctxf[((size_t)b * SS + qrow) * (HH * KDIM) + h * KDIM + c * 8] =
      *(uint4*)ob;
}

// ---------------- oproj: ctx[8192,512] @ Wo[512,64] via fp16 MFMA ------------
__global__ __launch_bounds__(256) void oproj_gemm(
    const _Float16* __restrict__ ctxf, const _Float16* __restrict__ woT,
    float* __restrict__ out) {
  __shared__ _Float16 Af[64 * 32], Bf[64 * 32];
  const int t = threadIdx.x, l = t & 63, w = t >> 6;
  const int lr = l & 31, hi = l >> 5;
  const int wr = w >> 1, wc = w & 1;
  const size_t rowbase = (size_t)blockIdx.x * 64;
  const int rl = l >> 2, ce = (l & 3) * 8;

  f32x16 acc = {};
  for (int kt = 0; kt < 16; ++kt) {
    const int k0 = kt * 32;
    __syncthreads();
    {
      const int row = w * 16;
      GLOAD_LDS16(ctxf + (rowbase + row + rl) * DD + k0 + ce, &Af[row * 32]);
      GLOAD_LDS16(woT + (size_t)(row + rl) * DD + k0 + ce, &Bf[row * 32]);
    }
    __syncthreads();
#pragma unroll
    for (int ks = 0; ks < 2; ++ks) {
      f16x8 af = *(const f16x8*)&Af[(wr * 32 + lr) * 32 + ks * 16 + hi * 8];
      f16x8 bf = *(const f16x8*)&Bf[(wc * 32 + lr) * 32 + ks * 16 + hi * 8];
      acc = __builtin_amdgcn_mfma_f32_32x32x16_f16(af, bf, acc, 0, 0, 0);
    }
  }
#pragma unroll
  for (int rr = 0; rr < 16; ++rr) {
    int m = (rr & 3) + 8 * (rr >> 2) + 4 * hi;
    out[(rowbase + wr * 32 + m) * 64 + wc * 32 + lr] = acc[rr];
  }
}

// ---------------- launch -----------------------------------------------------
extern "C" void kernel_launch(void* const* d_in, const int* in_sizes, int n_in,
                              void* d_out, int out_size, void* d_ws, size_t ws_size,
                              hipStream_t stream) {
  const float* x     = (const float*)d_in[0];
  const float* mask  = (const float*)d_in[1];
  const float* Wq    = (const float*)d_in[2];
  const float* Wk    = (const float*)d_in[3];
  const float* Wv    = (const float*)d_in[4];
  const float* Wo    = (const float*)d_in[5];
  const float* scales= (const float*)d_in[6];
  float* out = (float*)d_out;

  char* ws = (char*)d_ws;
  const size_t xb  = (size_t)BB * SS * DD * sizeof(_Float16);          // 8MB
  const size_t wb  = (size_t)3 * 512 * DD * sizeof(_Float16);          // 1.5MB
  const size_t wob = (size_t)64 * DD * sizeof(_Float16);               // 64KB
  const size_t qb  = (size_t)BB * HH * SS * KDIM * sizeof(_Float16);   // 8MB
  const size_t pob = (size_t)NSPLIT * BB * HH * SS * KDIM * sizeof(_Float16); // 33.5MB
  const size_t plib= (size_t)NSPLIT * BB * HH * SS * sizeof(float);    // 1MB

  _Float16* xfb  = (_Float16*)(ws);
  _Float16* wtfb = (_Float16*)(ws + xb);
  _Float16* woTb = (_Float16*)(ws + xb + wb);
  char* p = ws + xb + wb + wob;
  _Float16* qfb  = (_Float16*)(p);
  _Float16* kfb  = (_Float16*)(p + qb);
  _Float16* vTb  = (_Float16*)(p + 2 * qb);
  _Float16* ctxf = (_Float16*)(p + 3 * qb);
  _Float16* pob_p= (_Float16*)(p + 4 * qb);
  float*    pli_p= (float*)(p + 4 * qb + pob);
  (void)plib; (void)ws_size;

  convert_x<<<2048, 256, 0, stream>>>(x, xfb);
  convert_w<<<dim3(8, 24), 256, 0, stream>>>(Wq, Wk, Wv, wtfb);
  convert_wo<<<8, 256, 0, stream>>>(Wo, woTb);
  qkv_gemm<<<dim3(12, 64), 256, 0, stream>>>(xfb, wtfb, mask, scales,
                                             qfb, kfb, vTb);
  attn_kernel<<<dim3(SS / 128, BB * HH, NSPLIT), 256, 0, stream>>>(
      qfb, kfb, vTb, pob_p, pli_p);
  attn_combine<<<(BB * HH * SS) / 32, 256, 0, stream>>>(pob_p, pli_p, mask, ctxf);
  oproj_gemm<<<128, 256, 0, stream>>>(ctxf, woTb, out);
}